// Round 4
// baseline (196.884 us; speedup 1.0000x reference)
//
#include <hip/hip_runtime.h>
#include <math.h>

#define B 2
#define S 1024
#define H 1024
#define NIN 512
#define NP 32
#define SC 16
#define SCHUNK 64
#define NBLK 256
#define NTHR 256

// Sense-reversal grid barrier. cnt returns to 0 after every barrier, so the
// only init needed is the 8-byte memset in kernel_launch (poison-safety).
// Agent-scope acq/rel emits the L2 wb/inv needed across non-coherent XCDs.
__device__ __forceinline__ void grid_sync(unsigned* cnt, unsigned* gen) {
    __syncthreads();
    if (threadIdx.x == 0) {
        unsigned g = __hip_atomic_load(gen, __ATOMIC_RELAXED, __HIP_MEMORY_SCOPE_AGENT);
        unsigned old = __hip_atomic_fetch_add(cnt, 1u, __ATOMIC_ACQ_REL, __HIP_MEMORY_SCOPE_AGENT);
        if (old == NBLK - 1u) {
            __hip_atomic_store(cnt, 0u, __ATOMIC_RELAXED, __HIP_MEMORY_SCOPE_AGENT);
            __hip_atomic_fetch_add(gen, 1u, __ATOMIC_RELEASE, __HIP_MEMORY_SCOPE_AGENT);
        } else {
            while (__hip_atomic_load(gen, __ATOMIC_ACQUIRE, __HIP_MEMORY_SCOPE_AGENT) == g)
                __builtin_amdgcn_s_sleep(2);
        }
    }
    __syncthreads();
}

__global__ __launch_bounds__(NTHR)
void k_fused(const float* __restrict__ I, const float* __restrict__ act,
             const float* __restrict__ tmpl, const float* __restrict__ W,
             float* __restrict__ out, float* __restrict__ P,
             float* __restrict__ part, float* __restrict__ ctx, float* __restrict__ T,
             unsigned* cnt, unsigned* gen) {
    __shared__ float lds[NP * 256];   // 32 KB, re-carved per phase
    const int tid = threadIdx.x;
    const int bid = blockIdx.x;

    // ================= phase 1: P[b,s,n] =================
    {
        int t0 = bid * 8;                       // 8 tokens per block
        const float4* src = (const float4*)(act + (size_t)t0 * NIN);
        float4* dst = (float4*)lds;             // act rows: lds[0..4095]
        for (int k = tid; k < 8 * NIN / 4; k += NTHR) dst[k] = src[k];
        {   // template inverse norms -> lds[4096+n]
            int n = tid >> 3, s8 = tid & 7;
            const float* tr = tmpl + (size_t)n * NIN;
            float ss = 0.f;
#pragma unroll 16
            for (int k = 0; k < 64; ++k) { float x = tr[s8 + 8 * k]; ss += x * x; }
            ss += __shfl_xor(ss, 1); ss += __shfl_xor(ss, 2); ss += __shfl_xor(ss, 4);
            if (s8 == 0) lds[4096 + n] = 1.f / fmaxf(sqrtf(ss), 1e-12f);
        }
        __syncthreads();
        int tok = tid >> 5, sub = tid & 31;
        const float* arow = lds + tok * NIN;
        float ss = 0.f;
#pragma unroll
        for (int k = 0; k < 16; ++k) { float x = arow[sub + 32 * k]; ss += x * x; }
#pragma unroll
        for (int m = 16; m; m >>= 1) ss += __shfl_xor(ss, m);
        float inva = 1.f / fmaxf(sqrtf(ss), 1e-12f);
        float4 av[4];
#pragma unroll
        for (int q = 0; q < 4; ++q) av[q] = *(const float4*)(arow + sub * 4 + q * 128);
        float myd = 0.f;
#pragma unroll
        for (int n = 0; n < NP; ++n) {
            const float* trp = tmpl + (size_t)n * NIN + sub * 4;
            float d = 0.f;
#pragma unroll
            for (int q = 0; q < 4; ++q) {
                float4 tv = *(const float4*)(trp + q * 128);
                d += tv.x * av[q].x + tv.y * av[q].y + tv.z * av[q].z + tv.w * av[q].w;
            }
            d += __shfl_xor(d, 1); d += __shfl_xor(d, 2); d += __shfl_xor(d, 4);
            d += __shfl_xor(d, 8); d += __shfl_xor(d, 16);
            if (sub == n) myd = d;
        }
        float p = 1.f / (1.f + expf(-myd * inva * lds[4096 + sub]));
        P[(size_t)(t0 + tok) * NP + sub] = p;
    }
    grid_sync(cnt, gen);

    // ================= phase 2a: ctx partials =================
    {
        int ht = bid & 7, sc = (bid >> 3) & 15, b = bid >> 7;
        int hl = tid & 127;
        int g16 = (tid >> 7) * 16;
        int goff = g16;
        asm volatile("" : "+v"(goff));          // force vector loads of P
        int h = ht * 128 + hl;
        int s0 = sc * SCHUNK;
        const float* Pb = P + ((size_t)b * S + s0) * NP + goff;
        const float* Ip = I + ((size_t)b * S + s0) * H + h;
        float acc[16];
#pragma unroll
        for (int j = 0; j < 16; ++j) acc[j] = 0.f;
#pragma unroll 2
        for (int s = 0; s < SCHUNK; ++s) {
            float x = Ip[(size_t)s * H];
            float4 pv[4];
#pragma unroll
            for (int q = 0; q < 4; ++q) pv[q] = *(const float4*)(Pb + s * NP + 4 * q);
#pragma unroll
            for (int q = 0; q < 4; ++q) {
                acc[4*q+0] += x * pv[q].x; acc[4*q+1] += x * pv[q].y;
                acc[4*q+2] += x * pv[q].z; acc[4*q+3] += x * pv[q].w;
            }
        }
        size_t base = (((size_t)b * SC + sc) * NP + g16) * H + h;
#pragma unroll
        for (int j = 0; j < 16; ++j) part[base + (size_t)j * H] = acc[j];
    }
    grid_sync(cnt, gen);

    // ================= phase 2b: ctx reduce =================
    {
        int idx = bid * NTHR + tid;             // 0 .. B*NP*H-1
        int b = idx >> 15, rem = idx & 32767;
        float ssum = 0.f;
#pragma unroll
        for (int sc = 0; sc < SC; ++sc)
            ssum += part[((size_t)b * SC + sc) * (NP * H) + rem];
        ctx[idx] = ssum;
    }
    grid_sync(cnt, gen);

    // ================= phase 3: transform =================
    {
        int n = bid >> 3, rg8 = bid & 7;
        // nrm[b][n] = sum_s P  (deterministic, in-block)
        int bb = tid >> 7, j = tid & 127;
        int pj = j;
        asm volatile("" : "+v"(pj));            // force vector loads of P
        float ps = 0.f;
#pragma unroll
        for (int m = 0; m < 8; ++m)
            ps += P[((size_t)bb * S + pj + 128 * m) * NP + n];
        lds[tid] = ps;
        __syncthreads();
#pragma unroll
        for (int off = 64; off >= 1; off >>= 1) {
            if (j < off) lds[tid] += lds[tid + off];
            __syncthreads();
        }
        float inv0 = 1.f / (lds[0] + 1e-8f);
        float inv1 = 1.f / (lds[128] + 1e-8f);
        int w = tid >> 6, lane = tid & 63;
        const float4* c0g = (const float4*)(ctx + (size_t)n * H);
        const float4* c1g = (const float4*)(ctx + ((size_t)NP + n) * H);
        float4 c0[4], c1[4];
#pragma unroll
        for (int it = 0; it < 4; ++it) {
            float4 v = c0g[it * 64 + lane];
            c0[it] = make_float4(v.x * inv0, v.y * inv0, v.z * inv0, v.w * inv0);
            float4 u = c1g[it * 64 + lane];
            c1[it] = make_float4(u.x * inv1, u.y * inv1, u.z * inv1, u.w * inv1);
        }
        for (int rg = 0; rg < 8; ++rg) {
            int row0 = rg8 * 128 + rg * 16 + w * 4;
            const float4* Wr = (const float4*)(W + ((size_t)n * H + row0) * H);
            float a0[4] = {0.f,0.f,0.f,0.f}, a1[4] = {0.f,0.f,0.f,0.f};
#pragma unroll
            for (int it = 0; it < 4; ++it) {
#pragma unroll
                for (int r = 0; r < 4; ++r) {
                    float4 wv = Wr[r * 256 + it * 64 + lane];
                    a0[r] += wv.x*c0[it].x + wv.y*c0[it].y + wv.z*c0[it].z + wv.w*c0[it].w;
                    a1[r] += wv.x*c1[it].x + wv.y*c1[it].y + wv.z*c1[it].z + wv.w*c1[it].w;
                }
            }
#pragma unroll
            for (int r = 0; r < 4; ++r) {
#pragma unroll
                for (int off = 32; off; off >>= 1) {
                    a0[r] += __shfl_xor(a0[r], off);
                    a1[r] += __shfl_xor(a1[r], off);
                }
            }
            if (lane == 0) {
#pragma unroll
                for (int r = 0; r < 4; ++r) {
                    T[(size_t)n * H + row0 + r] = a0[r];
                    T[((size_t)NP + n) * H + row0 + r] = a1[r];
                }
            }
        }
    }
    grid_sync(cnt, gen);

    // ================= phase 4: combine =================
    {
        int b = bid >> 7, ht = (bid >> 5) & 3, sc2 = bid & 31;
        int h0 = ht * 256;
        for (int k = tid; k < NP * 256; k += NTHR) {
            int n = k >> 8, h = k & 255;
            lds[k] = T[((size_t)b * NP + n) * H + h0 + h];
        }
        __syncthreads();
        unsigned poff = 0;
        asm volatile("" : "+v"(poff));          // force vector loads of P
#pragma unroll
        for (int u = 0; u < 2; ++u) {
            int s0 = (sc2 * 2 + u) * 16;
            const float4* P4 = (const float4*)(P + ((size_t)b * S + s0) * NP + poff);
            float acc[16];
#pragma unroll
            for (int s = 0; s < 16; ++s) acc[s] = 0.f;
#pragma unroll
            for (int n0 = 0; n0 < NP; n0 += 4) {
                float t0v = lds[(n0 + 0) * 256 + tid];
                float t1v = lds[(n0 + 1) * 256 + tid];
                float t2v = lds[(n0 + 2) * 256 + tid];
                float t3v = lds[(n0 + 3) * 256 + tid];
#pragma unroll
                for (int s = 0; s < 16; ++s) {
                    float4 pv = P4[s * 8 + n0 / 4];
                    acc[s] += t0v * pv.x + t1v * pv.y + t2v * pv.z + t3v * pv.w;
                }
            }
#pragma unroll
            for (int s = 0; s < 16; ++s)
                out[((size_t)b * S + s0 + s) * H + h0 + tid] = acc[s];
        }
    }
}

extern "C" void kernel_launch(void* const* d_in, const int* in_sizes, int n_in,
                              void* d_out, int out_size, void* d_ws, size_t ws_size,
                              hipStream_t stream) {
    const float* I    = (const float*)d_in[0];  // [B,S,H]
    const float* act  = (const float*)d_in[1];  // [B,S,NIN]
    const float* tmpl = (const float*)d_in[2];  // [NP,NIN]
    const float* W    = (const float*)d_in[3];  // [NP*H,H]
    float* out  = (float*)d_out;                // combined [B,S,H]
    float* Pout = out + (size_t)B * S * H;      // process_activations [B,S,NP]

    unsigned* cnt = (unsigned*)d_ws;            // [0]=cnt, [1]=gen
    float* fws  = (float*)d_ws;
    float* part = fws + 16;                     // B*SC*NP*H
    float* ctx  = part + (size_t)B * SC * NP * H;
    float* T    = ctx + (size_t)B * NP * H;

    hipMemsetAsync(d_ws, 0, 2 * sizeof(unsigned), stream);
    k_fused<<<NBLK, NTHR, 0, stream>>>(I, act, tmpl, W, out, Pout, part, ctx, T,
                                       cnt, cnt + 1);
}

// Round 5
// 75.044 us; speedup vs baseline: 2.6236x; 2.6236x over previous
//
#include <hip/hip_runtime.h>
#include <math.h>

#define B 2
#define S 1024
#define H 1024
#define NIN 512
#define NP 32
#define SC2 32           // s-chunks of 32 tokens for ctx partials

__device__ __forceinline__ float dot4(float4 a, float4 b) {
    return a.x * b.x + a.y * b.y + a.z * b.z + a.w * b.w;
}

// ---------- K1: fused template-norm + act-norm + pattern + nrm atomics ----------
// grid = B*S/8 = 256 blocks; block 256 = 8 tokens x 32 sub-lanes
__global__ __launch_bounds__(256)
void k_pattern(const float* __restrict__ act, const float* __restrict__ tmpl,
               float* __restrict__ P, float* __restrict__ nrm) {
    __shared__ float act_lds[8][NIN];   // 16 KB
    __shared__ float invn[NP];
    __shared__ float psum[8][NP];
    int tid = threadIdx.x;
    int t0 = blockIdx.x * 8;
    int b  = t0 >> 10;

    {   // stage 8 act rows (float4, coalesced)
        const float4* src = (const float4*)(act + (size_t)t0 * NIN);
        float4* dst = (float4*)(&act_lds[0][0]);
        for (int k = tid; k < 8 * NIN / 4; k += 256) dst[k] = src[k];
    }
    {   // template inverse norms: 8 lanes per template (tmpl = 64 KB, L1/L2)
        int n = tid >> 3, s8 = tid & 7;
        const float* tr = tmpl + (size_t)n * NIN;
        float ss = 0.f;
#pragma unroll 16
        for (int k = 0; k < 64; ++k) { float x = tr[s8 + 8 * k]; ss += x * x; }
        ss += __shfl_xor(ss, 1); ss += __shfl_xor(ss, 2); ss += __shfl_xor(ss, 4);
        if (s8 == 0) invn[n] = 1.f / fmaxf(sqrtf(ss), 1e-12f);
    }
    __syncthreads();

    int tok = tid >> 5, sub = tid & 31;
    const float* arow = &act_lds[tok][0];
    float ss = 0.f;
#pragma unroll
    for (int k = 0; k < 16; ++k) { float x = arow[sub + 32 * k]; ss += x * x; }
#pragma unroll
    for (int m = 16; m; m >>= 1) ss += __shfl_xor(ss, m);
    float inva = 1.f / fmaxf(sqrtf(ss), 1e-12f);

    float4 av[4];
#pragma unroll
    for (int q = 0; q < 4; ++q) av[q] = *(const float4*)(arow + sub * 4 + q * 128);

    float myd = 0.f;
#pragma unroll
    for (int n = 0; n < NP; ++n) {
        const float* trp = tmpl + (size_t)n * NIN + sub * 4;
        float d = 0.f;
#pragma unroll
        for (int q = 0; q < 4; ++q) d += dot4(*(const float4*)(trp + q * 128), av[q]);
        d += __shfl_xor(d, 1); d += __shfl_xor(d, 2); d += __shfl_xor(d, 4);
        d += __shfl_xor(d, 8); d += __shfl_xor(d, 16);
        if (sub == n) myd = d;
    }
    float p = 1.f / (1.f + expf(-myd * inva * invn[sub]));
    P[(size_t)(t0 + tok) * NP + sub] = p;
    psum[tok][sub] = p;
    __syncthreads();
    if (tid < NP) {
        float s = 0.f;
#pragma unroll
        for (int t = 0; t < 8; ++t) s += psum[t][tid];
        unsafeAtomicAdd(&nrm[b * NP + tid], s);
    }
}

// ---------- K2: ctx partials. thread = 4h (float4) x 8n; block = 256h x 32n ----------
// grid = B * 4 h-tiles * 32 s-chunks = 256; block 256 = 64 hq x 4 ng
__global__ __launch_bounds__(256)
void k_ctx_partial(const float* __restrict__ I, const float* __restrict__ P,
                   float* __restrict__ part) {
    __shared__ float4 Pl4[SC2 * NP / 4];   // 32 s x 32 n = 4 KB
    int bid = blockIdx.x;
    int sc = bid & 31, ht = (bid >> 5) & 3, b = bid >> 7;
    int tid = threadIdx.x;
    int s0 = sc * 32;
    // stage P[32 s][32 n] as 256 float4
    Pl4[tid] = ((const float4*)(P + ((size_t)b * S + s0) * NP))[tid];
    __syncthreads();

    int hq = tid & 63, ng = tid >> 6;      // ng uniform per wave
    int h = ht * 256 + hq * 4;
    const float4* I4 = (const float4*)(I) + ((size_t)b * S + s0) * (H / 4) + (h >> 2);
    float4 acc[8];
#pragma unroll
    for (int j = 0; j < 8; ++j) acc[j] = make_float4(0.f, 0.f, 0.f, 0.f);
#pragma unroll 4
    for (int s = 0; s < 32; ++s) {
        float4 iv = I4[s * (H / 4)];
        float4 pa = Pl4[s * 8 + ng * 2];       // wave-uniform ds_read_b128
        float4 pb = Pl4[s * 8 + ng * 2 + 1];
        acc[0].x += iv.x * pa.x; acc[0].y += iv.y * pa.x; acc[0].z += iv.z * pa.x; acc[0].w += iv.w * pa.x;
        acc[1].x += iv.x * pa.y; acc[1].y += iv.y * pa.y; acc[1].z += iv.z * pa.y; acc[1].w += iv.w * pa.y;
        acc[2].x += iv.x * pa.z; acc[2].y += iv.y * pa.z; acc[2].z += iv.z * pa.z; acc[2].w += iv.w * pa.z;
        acc[3].x += iv.x * pa.w; acc[3].y += iv.y * pa.w; acc[3].z += iv.z * pa.w; acc[3].w += iv.w * pa.w;
        acc[4].x += iv.x * pb.x; acc[4].y += iv.y * pb.x; acc[4].z += iv.z * pb.x; acc[4].w += iv.w * pb.x;
        acc[5].x += iv.x * pb.y; acc[5].y += iv.y * pb.y; acc[5].z += iv.z * pb.y; acc[5].w += iv.w * pb.y;
        acc[6].x += iv.x * pb.z; acc[6].y += iv.y * pb.z; acc[6].z += iv.z * pb.z; acc[6].w += iv.w * pb.z;
        acc[7].x += iv.x * pb.w; acc[7].y += iv.y * pb.w; acc[7].z += iv.z * pb.w; acc[7].w += iv.w * pb.w;
    }
    int n0 = ng * 8;
    size_t base = ((size_t)(b * SC2 + sc) * NP + n0) * H + h;
#pragma unroll
    for (int j = 0; j < 8; ++j)
        *(float4*)(part + base + (size_t)j * H) = acc[j];
}

// ---------- K3: ctx = sum over 32 partials ----------
__global__ __launch_bounds__(256)
void k_ctx_reduce(const float* __restrict__ part, float* __restrict__ ctx) {
    int idx = blockIdx.x * 256 + threadIdx.x;   // 0 .. B*NP*H-1
    int b = idx >> 15, rem = idx & 32767;
    float s = 0.f;
#pragma unroll
    for (int sc = 0; sc < SC2; ++sc)
        s += part[((size_t)b * SC2 + sc) * (NP * H) + rem];
    ctx[idx] = s;
}

// ---------- K4: T[b,n,k] = sum_h (ctx[b,n,h]/nrm[b,n]) * W[n,k,h] ----------
// grid = NP * 128 = 4096; block 256 = 4 waves, 2 rows/wave, 8 rows/block
__global__ __launch_bounds__(256)
void k_transform(const float* __restrict__ W, const float* __restrict__ ctx,
                 const float* __restrict__ nrm, float* __restrict__ T) {
    __shared__ float4 cl4[512];   // 8 KB: scaled ctx rows for both batches
    int bid = blockIdx.x;
    int n = bid >> 7, rg = bid & 127;
    int tid = threadIdx.x;
    float inv0 = 1.f / (nrm[n] + 1e-8f);
    float inv1 = 1.f / (nrm[NP + n] + 1e-8f);
    {
        float4 v = ((const float4*)(ctx + (size_t)n * H))[tid];
        cl4[tid] = make_float4(v.x * inv0, v.y * inv0, v.z * inv0, v.w * inv0);
        float4 u = ((const float4*)(ctx + ((size_t)NP + n) * H))[tid];
        cl4[256 + tid] = make_float4(u.x * inv1, u.y * inv1, u.z * inv1, u.w * inv1);
    }
    __syncthreads();

    int w = tid >> 6, lane = tid & 63;
    int r0 = rg * 8 + w * 2;                   // 2 consecutive W rows per wave
    const float4* W0 = (const float4*)(W + ((size_t)n * H + r0) * H);
    const float4* W1 = W0 + (H / 4);
    float a00 = 0.f, a01 = 0.f, a10 = 0.f, a11 = 0.f;
#pragma unroll
    for (int it = 0; it < 4; ++it) {
        int ix = it * 64 + lane;
        float4 f0 = cl4[ix];
        float4 f1 = cl4[256 + ix];
        float4 w0 = W0[ix];
        float4 w1 = W1[ix];
        a00 += dot4(w0, f0); a01 += dot4(w0, f1);
        a10 += dot4(w1, f0); a11 += dot4(w1, f1);
    }
#pragma unroll
    for (int off = 32; off; off >>= 1) {
        a00 += __shfl_xor(a00, off); a01 += __shfl_xor(a01, off);
        a10 += __shfl_xor(a10, off); a11 += __shfl_xor(a11, off);
    }
    if (lane == 0) {
        T[(size_t)n * H + r0] = a00;
        T[((size_t)NP + n) * H + r0] = a01;
        T[(size_t)n * H + r0 + 1] = a10;
        T[((size_t)NP + n) * H + r0 + 1] = a11;
    }
}

// ---------- K5: combined[b,s,h] = sum_n T[b,n,h] * P[b,s,n]; P via scalar loads ----------
// grid = B * 64 * 4 = 512; block 256, thread owns one h
__global__ __launch_bounds__(256)
void k_combine(const float* __restrict__ T, const float* __restrict__ P,
               float* __restrict__ out) {
    __shared__ float Tl[NP][256];   // 32 KB
    int bid = blockIdx.x;
    int ht = bid & 3, sc = (bid >> 2) & 63, b = bid >> 8;
    int tid = threadIdx.x;
    int h0 = ht * 256;
    {   // stage T tile as float4
        float4* dst = (float4*)(&Tl[0][0]);
        for (int k = tid; k < NP * 64; k += 256) {
            int n = k >> 6, hq = k & 63;
            dst[k] = *(const float4*)(T + ((size_t)b * NP + n) * H + h0 + hq * 4);
        }
    }
    __syncthreads();
    int s0 = sc * 16;
    const float* Pb = P + ((size_t)b * S + s0) * NP;   // block-uniform -> s_load
    float acc[16];
#pragma unroll
    for (int s = 0; s < 16; ++s) acc[s] = 0.f;
#pragma unroll
    for (int n0 = 0; n0 < NP; n0 += 4) {
        float t0v = Tl[n0 + 0][tid];
        float t1v = Tl[n0 + 1][tid];
        float t2v = Tl[n0 + 2][tid];
        float t3v = Tl[n0 + 3][tid];
#pragma unroll
        for (int s = 0; s < 16; ++s) {
            const float* pr = Pb + s * NP + n0;
            acc[s] += t0v * pr[0] + t1v * pr[1] + t2v * pr[2] + t3v * pr[3];
        }
    }
#pragma unroll
    for (int s = 0; s < 16; ++s)
        out[((size_t)b * S + s0 + s) * H + h0 + tid] = acc[s];
}

extern "C" void kernel_launch(void* const* d_in, const int* in_sizes, int n_in,
                              void* d_out, int out_size, void* d_ws, size_t ws_size,
                              hipStream_t stream) {
    const float* I    = (const float*)d_in[0];  // [B,S,H]
    const float* act  = (const float*)d_in[1];  // [B,S,NIN]
    const float* tmpl = (const float*)d_in[2];  // [NP,NIN]
    const float* W    = (const float*)d_in[3];  // [NP*H,H]
    float* out  = (float*)d_out;                // combined [B,S,H]
    float* Pout = out + (size_t)B * S * H;      // process_activations [B,S,NP]

    float* ws   = (float*)d_ws;
    float* nrm  = ws;                                   // B*NP = 64
    float* part = nrm + 64;                             // B*SC2*NP*H = 8M floats
    float* ctx  = part + (size_t)B * SC2 * NP * H;      // B*NP*H
    float* T    = ctx + (size_t)B * NP * H;             // B*NP*H

    hipMemsetAsync(nrm, 0, (size_t)B * NP * sizeof(float), stream);
    k_pattern    <<<B * S / 8,        256, 0, stream>>>(act, tmpl, Pout, nrm);
    k_ctx_partial<<<B * 4 * SC2,      256, 0, stream>>>(I, Pout, part);
    k_ctx_reduce <<<B * NP * H / 256, 256, 0, stream>>>(part, ctx);
    k_transform  <<<NP * 128,         256, 0, stream>>>(W, ctx, nrm, T);
    k_combine    <<<B * 64 * 4,       256, 0, stream>>>(T, Pout, out);
}